// Round 1
// baseline (3074.392 us; speedup 1.0000x reference)
//
#include <hip/hip_runtime.h>

#define FF 128

// Unified fp32 matmul kernel: out[n][j] = act( dot(pre(xin[n]), W[j]) + bias[j] (+ addsrc[n][j]) )
// PRE: 0=identity, 1=row L2-normalize, 2=elementwise sqrt
// Each wave handles 4 nodes; lane computes feature j=lane (and j=lane+64 if OUT==128).
template<int OUT, int PRE, int ADD, int RELU>
__global__ __launch_bounds__(256, 2)
void mm_kernel(const float* __restrict__ xin, const float* __restrict__ W,
               const float* __restrict__ bias, const float* __restrict__ addsrc,
               float* __restrict__ out, int N)
{
    __shared__ float sW[OUT * 132];        // pitch 132: 16B-aligned rows, even bank spread
    __shared__ float sX[4 * 4 * 128];      // [wave][nodeslot][k]
    const int tid = threadIdx.x;

    // cooperative stage of W into LDS
    for (int i = tid; i < OUT * 128; i += 256) {
        int j = i >> 7, k = i & 127;
        sW[j * 132 + k] = W[i];
    }
    __syncthreads();

    const int wave = tid >> 6, lane = tid & 63;
    const int base = (blockIdx.x * 4 + wave) * 4;
    float* xw = &sX[wave * 4 * 128];

    #pragma unroll
    for (int s = 0; s < 4; ++s) {
        int n = base + s;
        float f0 = 0.f, f1 = 0.f;
        if (n < N) {
            f0 = xin[(size_t)n * FF + lane];
            f1 = xin[(size_t)n * FF + 64 + lane];
        }
        if constexpr (PRE == 1) {
            float ss = f0 * f0 + f1 * f1;
            #pragma unroll
            for (int off = 32; off; off >>= 1) ss += __shfl_xor(ss, off);
            float scl = 1.0f / fmaxf(sqrtf(ss), 1e-12f);
            f0 *= scl; f1 *= scl;
        } else if constexpr (PRE == 2) {
            f0 = sqrtf(f0); f1 = sqrtf(f1);
        }
        xw[s * 128 + lane] = f0;
        xw[s * 128 + 64 + lane] = f1;
        // wave-local LDS: no barrier needed
    }

    float acc0[4] = {0.f, 0.f, 0.f, 0.f};
    float acc1[4] = {0.f, 0.f, 0.f, 0.f};

    #pragma unroll 4
    for (int k = 0; k < 128; k += 4) {
        float4 w0 = *(const float4*)&sW[lane * 132 + k];
        float4 w1v;
        if constexpr (OUT == 128) w1v = *(const float4*)&sW[(lane + 64) * 132 + k];
        #pragma unroll
        for (int s = 0; s < 4; ++s) {
            float4 xv = *(const float4*)&xw[s * 128 + k];  // broadcast read
            acc0[s] = fmaf(xv.x, w0.x, fmaf(xv.y, w0.y, fmaf(xv.z, w0.z, fmaf(xv.w, w0.w, acc0[s]))));
            if constexpr (OUT == 128)
                acc1[s] = fmaf(xv.x, w1v.x, fmaf(xv.y, w1v.y, fmaf(xv.z, w1v.z, fmaf(xv.w, w1v.w, acc1[s]))));
        }
    }

    float b0 = bias[lane];
    float b1 = (OUT == 128) ? bias[lane + 64] : 0.f;
    #pragma unroll
    for (int s = 0; s < 4; ++s) {
        int n = base + s;
        if (n >= N) continue;
        float v0 = acc0[s] + b0;
        if constexpr (ADD) v0 += addsrc[(size_t)n * OUT + lane];
        if constexpr (RELU) v0 = fmaxf(v0, 0.f);
        out[(size_t)n * OUT + lane] = v0;
        if constexpr (OUT == 128) {
            float v1 = acc1[s] + b1;
            if constexpr (ADD) v1 += addsrc[(size_t)n * OUT + lane + 64];
            if constexpr (RELU) v1 = fmaxf(v1, 0.f);
            out[(size_t)n * OUT + lane + 64] = v1;
        }
    }
}

// agg[dst] += val * h[src]^2, 32 threads per edge (4 feats each as float4 gather)
__global__ __launch_bounds__(256)
void edge_kernel(const float* __restrict__ h, const int* __restrict__ src,
                 const int* __restrict__ dst, const float* __restrict__ val,
                 float* __restrict__ agg, int E)
{
    int t = blockIdx.x * 256 + threadIdx.x;
    int e = t >> 5;
    if (e >= E) return;
    int c = (t & 31) << 2;
    int s = src[e], d = dst[e];
    float v = val[e];
    const float4 hv = *(const float4*)&h[(size_t)s * FF + c];
    float* ap = &agg[(size_t)d * FF + c];
    atomicAdd(ap + 0, v * hv.x * hv.x);
    atomicAdd(ap + 1, v * hv.y * hv.y);
    atomicAdd(ap + 2, v * hv.z * hv.z);
    atomicAdd(ap + 3, v * hv.w * hv.w);
}

extern "C" void kernel_launch(void* const* d_in, const int* in_sizes, int n_in,
                              void* d_out, int out_size, void* d_ws, size_t ws_size,
                              hipStream_t stream) {
    const float* x    = (const float*)d_in[0];
    const int*   esrc = (const int*)d_in[1];
    const int*   edst = (const int*)d_in[2];
    const float* eval = (const float*)d_in[3];
    const float* pw0  = (const float*)d_in[4];
    const float* pb0  = (const float*)d_in[5];
    const float* f1w0 = (const float*)d_in[6];
    const float* f1b0 = (const float*)d_in[7];
    const float* f2w0 = (const float*)d_in[8];
    const float* f2b0 = (const float*)d_in[9];
    const float* pw1  = (const float*)d_in[10];
    const float* pb1  = (const float*)d_in[11];
    const float* f1w1 = (const float*)d_in[12];
    const float* f1b1 = (const float*)d_in[13];
    const float* f2w1 = (const float*)d_in[14];
    const float* f2b1 = (const float*)d_in[15];
    float* out = (float*)d_out;

    const int N = in_sizes[0] / FF;     // 50000
    const int E = in_sizes[1];          // 800000

    char* ws = (char*)d_ws;
    const size_t rowsz = (size_t)N * FF * sizeof(float);   // 25.6 MB
    float* h   = (float*)(ws);
    float* agg = (float*)(ws + rowsz);
    float* tmp = (float*)(ws + 2 * rowsz);
    float* x1  = (float*)(ws + 3 * rowsz);

    const int mmblocks = (N + 15) / 16;
    const int eblocks  = (E * 32 + 255) / 256;
    dim3 B(256);

    // ---- layer 0 (128 -> 128, relu) ----
    mm_kernel<128, 1, 0, 1><<<mmblocks, B, 0, stream>>>(x, pw0, pb0, nullptr, h, N);
    hipMemsetAsync(agg, 0, rowsz, stream);
    edge_kernel<<<eblocks, B, 0, stream>>>(h, esrc, edst, eval, agg, E);
    mm_kernel<128, 0, 0, 0><<<mmblocks, B, 0, stream>>>(h, f1w0, f1b0, nullptr, tmp, N);
    mm_kernel<128, 2, 1, 1><<<mmblocks, B, 0, stream>>>(agg, f2w0, f2b0, tmp, x1, N);

    // ---- layer 1 (128 -> 64, no act) ----
    mm_kernel<128, 1, 0, 1><<<mmblocks, B, 0, stream>>>(x1, pw1, pb1, nullptr, h, N);
    hipMemsetAsync(agg, 0, rowsz, stream);
    edge_kernel<<<eblocks, B, 0, stream>>>(h, esrc, edst, eval, agg, E);
    mm_kernel<64, 0, 0, 0><<<mmblocks, B, 0, stream>>>(h, f1w1, f1b1, nullptr, tmp, N);
    mm_kernel<64, 2, 1, 0><<<mmblocks, B, 0, stream>>>(agg, f2w1, f2b1, tmp, out, N);
}

// Round 2
// 695.483 us; speedup vs baseline: 4.4205x; 4.4205x over previous
//
#include <hip/hip_runtime.h>

#define FF 128

// ---------------------------------------------------------------------------
// Unified fp32 matmul kernel: out[n][j] = act( dot(pre(xin[n]), W[j]) + bias[j]
//                                              (+ addsrc[n][j]) )
// PRE: 0=identity, 1=row L2-normalize, 2=elementwise sqrt
// Each wave handles 4 nodes; lane computes feature j=lane (and j=lane+64 if OUT==128).
// ADD may alias out (same-thread same-index read-then-write).
// ---------------------------------------------------------------------------
template<int OUT, int PRE, int ADD, int RELU>
__global__ __launch_bounds__(256, 2)
void mm_kernel(const float* __restrict__ xin, const float* __restrict__ W,
               const float* __restrict__ bias, const float* __restrict__ addsrc,
               float* __restrict__ out, int N)
{
    __shared__ float sW[OUT * 132];        // pitch 132: 16B-aligned rows, even bank spread
    __shared__ float sX[4 * 4 * 128];      // [wave][nodeslot][k]
    const int tid = threadIdx.x;

    for (int i = tid; i < OUT * 128; i += 256) {
        int j = i >> 7, k = i & 127;
        sW[j * 132 + k] = W[i];
    }
    __syncthreads();

    const int wave = tid >> 6, lane = tid & 63;
    const int base = (blockIdx.x * 4 + wave) * 4;
    float* xw = &sX[wave * 4 * 128];

    #pragma unroll
    for (int s = 0; s < 4; ++s) {
        int n = base + s;
        float f0 = 0.f, f1 = 0.f;
        if (n < N) {
            f0 = xin[(size_t)n * FF + lane];
            f1 = xin[(size_t)n * FF + 64 + lane];
        }
        if constexpr (PRE == 1) {
            float ss = f0 * f0 + f1 * f1;
            #pragma unroll
            for (int off = 32; off; off >>= 1) ss += __shfl_xor(ss, off);
            float scl = 1.0f / fmaxf(sqrtf(ss), 1e-12f);
            f0 *= scl; f1 *= scl;
        } else if constexpr (PRE == 2) {
            f0 = sqrtf(f0); f1 = sqrtf(f1);
        }
        xw[s * 128 + lane] = f0;
        xw[s * 128 + 64 + lane] = f1;
        // wave-local LDS: no barrier needed
    }

    float acc0[4] = {0.f, 0.f, 0.f, 0.f};
    float acc1[4] = {0.f, 0.f, 0.f, 0.f};

    #pragma unroll 4
    for (int k = 0; k < 128; k += 4) {
        float4 w0 = *(const float4*)&sW[lane * 132 + k];
        float4 w1v;
        if constexpr (OUT == 128) w1v = *(const float4*)&sW[(lane + 64) * 132 + k];
        #pragma unroll
        for (int s = 0; s < 4; ++s) {
            float4 xv = *(const float4*)&xw[s * 128 + k];  // broadcast read
            acc0[s] = fmaf(xv.x, w0.x, fmaf(xv.y, w0.y, fmaf(xv.z, w0.z, fmaf(xv.w, w0.w, acc0[s]))));
            if constexpr (OUT == 128)
                acc1[s] = fmaf(xv.x, w1v.x, fmaf(xv.y, w1v.y, fmaf(xv.z, w1v.z, fmaf(xv.w, w1v.w, acc1[s]))));
        }
    }

    float b0 = bias[lane];
    float b1 = (OUT == 128) ? bias[lane + 64] : 0.f;
    #pragma unroll
    for (int s = 0; s < 4; ++s) {
        int n = base + s;
        if (n >= N) continue;
        float v0 = acc0[s] + b0;
        if constexpr (ADD) v0 += addsrc[(size_t)n * OUT + lane];
        if constexpr (RELU) v0 = fmaxf(v0, 0.f);
        out[(size_t)n * OUT + lane] = v0;
        if constexpr (OUT == 128) {
            float v1 = acc1[s] + b1;
            if constexpr (ADD) v1 += addsrc[(size_t)n * OUT + lane + 64];
            if constexpr (RELU) v1 = fmaxf(v1, 0.f);
            out[(size_t)n * OUT + lane + 64] = v1;
        }
    }
}

// ---------------------------------------------------------------------------
// CSR build: histogram -> exclusive scan -> scatter packed {src,val} by dst
// ---------------------------------------------------------------------------
__global__ __launch_bounds__(256)
void hist_kernel(const int* __restrict__ dst, int* __restrict__ counts, int E)
{
    int e = blockIdx.x * 256 + threadIdx.x;
    if (e < E) atomicAdd(&counts[dst[e]], 1);
}

// Single-block exclusive scan over counts[0..N). Writes offsets[0..N] and
// rewrites counts[] in place with the exclusive prefix (= scatter cursor).
__global__ __launch_bounds__(1024)
void scan_kernel(int* __restrict__ counts, int* __restrict__ offsets, int N, int E)
{
    __shared__ int s[1024];
    const int t = threadIdx.x;
    const int C = (N + 1023) / 1024;
    const int lo = t * C, hi = min(lo + C, N);

    int partial = 0;
    for (int i = lo; i < hi; ++i) partial += counts[i];
    s[t] = partial;
    __syncthreads();
    // Hillis-Steele inclusive scan of the 1024 partials
    #pragma unroll
    for (int off = 1; off < 1024; off <<= 1) {
        int v = (t >= off) ? s[t - off] : 0;
        __syncthreads();
        s[t] += v;
        __syncthreads();
    }
    int running = s[t] - partial;   // exclusive base for this chunk
    for (int i = lo; i < hi; ++i) {
        int c = counts[i];
        offsets[i] = running;
        counts[i] = running;        // cursor
        running += c;
    }
    if (t == 0) offsets[N] = E;
}

__global__ __launch_bounds__(256)
void scatter_kernel(const int* __restrict__ src, const int* __restrict__ dst,
                    const float* __restrict__ val, int* __restrict__ cursor,
                    int2* __restrict__ edata, int E)
{
    int e = blockIdx.x * 256 + threadIdx.x;
    if (e >= E) return;
    int pos = atomicAdd(&cursor[dst[e]], 1);
    edata[pos] = make_int2(src[e], __float_as_int(val[e]));
}

// ---------------------------------------------------------------------------
// CSR aggregation: one wave per dst node, lane l holds feats {2l, 2l+1}.
// agg[d] = sum over incident edges of val * h[src]^2.  No atomics.
// ---------------------------------------------------------------------------
__global__ __launch_bounds__(256)
void agg_kernel(const float* __restrict__ h, const int* __restrict__ offsets,
                const int2* __restrict__ edata, float* __restrict__ agg, int N)
{
    const int w = blockIdx.x * 4 + (threadIdx.x >> 6);
    if (w >= N) return;
    const int lane = threadIdx.x & 63;
    const int beg = offsets[w], end = offsets[w + 1];

    float2 a0 = {0.f, 0.f}, a1 = {0.f, 0.f};
    int e = beg;
    for (; e + 1 < end; e += 2) {
        int2 ed0 = edata[e];
        int2 ed1 = edata[e + 1];
        float2 h0 = *(const float2*)&h[(size_t)ed0.x * FF + lane * 2];
        float2 h1 = *(const float2*)&h[(size_t)ed1.x * FF + lane * 2];
        float v0 = __int_as_float(ed0.y);
        float v1 = __int_as_float(ed1.y);
        a0.x = fmaf(v0 * h0.x, h0.x, a0.x);
        a0.y = fmaf(v0 * h0.y, h0.y, a0.y);
        a1.x = fmaf(v1 * h1.x, h1.x, a1.x);
        a1.y = fmaf(v1 * h1.y, h1.y, a1.y);
    }
    if (e < end) {
        int2 ed = edata[e];
        float2 hv = *(const float2*)&h[(size_t)ed.x * FF + lane * 2];
        float v = __int_as_float(ed.y);
        a0.x = fmaf(v * hv.x, hv.x, a0.x);
        a0.y = fmaf(v * hv.y, hv.y, a0.y);
    }
    float2 res = {a0.x + a1.x, a0.y + a1.y};
    *(float2*)&agg[(size_t)w * FF + lane * 2] = res;
}

// ---------------------------------------------------------------------------
extern "C" void kernel_launch(void* const* d_in, const int* in_sizes, int n_in,
                              void* d_out, int out_size, void* d_ws, size_t ws_size,
                              hipStream_t stream) {
    const float* x    = (const float*)d_in[0];
    const int*   esrc = (const int*)d_in[1];
    const int*   edst = (const int*)d_in[2];
    const float* eval = (const float*)d_in[3];
    const float* pw0  = (const float*)d_in[4];
    const float* pb0  = (const float*)d_in[5];
    const float* f1w0 = (const float*)d_in[6];
    const float* f1b0 = (const float*)d_in[7];
    const float* f2w0 = (const float*)d_in[8];
    const float* f2b0 = (const float*)d_in[9];
    const float* pw1  = (const float*)d_in[10];
    const float* pb1  = (const float*)d_in[11];
    const float* f1w1 = (const float*)d_in[12];
    const float* f1b1 = (const float*)d_in[13];
    const float* f2w1 = (const float*)d_in[14];
    const float* f2b1 = (const float*)d_in[15];
    float* out = (float*)d_out;

    const int N = in_sizes[0] / FF;     // 50000
    const int E = in_sizes[1];          // 800000

    char* ws = (char*)d_ws;
    const size_t rowsz = (size_t)N * FF * sizeof(float);          // 25.6 MB
    const size_t A = 256;                                          // alignment
    size_t off = 0;
    float* h   = (float*)(ws + off); off += rowsz;
    float* agg = (float*)(ws + off); off += rowsz;
    float* x1  = (float*)(ws + off); off += rowsz;
    int* offsets = (int*)(ws + off); off += ((size_t)(N + 1) * 4 + A - 1) / A * A;
    int* cursor  = (int*)(ws + off); off += ((size_t)N * 4 + A - 1) / A * A;
    int2* edata  = (int2*)(ws + off);

    const int mmblocks = (N + 15) / 16;
    const int nodeblocks = (N + 3) / 4;
    const int eblocks = (E + 255) / 256;
    dim3 B(256);

    // ---- CSR build (dst-sorted), reused by both layers ----
    hipMemsetAsync(cursor, 0, (size_t)N * 4, stream);
    hist_kernel<<<eblocks, B, 0, stream>>>(edst, cursor, E);
    scan_kernel<<<1, 1024, 0, stream>>>(cursor, offsets, N, E);
    scatter_kernel<<<eblocks, B, 0, stream>>>(esrc, edst, eval, cursor, edata, E);

    // ---- layer 0 (128 -> 128, relu) ----
    mm_kernel<128, 1, 0, 1><<<mmblocks, B, 0, stream>>>(x, pw0, pb0, nullptr, h, N);
    agg_kernel<<<nodeblocks, B, 0, stream>>>(h, offsets, edata, agg, N);
    mm_kernel<128, 0, 0, 0><<<mmblocks, B, 0, stream>>>(h, f1w0, f1b0, nullptr, x1, N);
    mm_kernel<128, 2, 1, 1><<<mmblocks, B, 0, stream>>>(agg, f2w0, f2b0, x1, x1, N);

    // ---- layer 1 (128 -> 64, no act) ----
    mm_kernel<128, 1, 0, 1><<<mmblocks, B, 0, stream>>>(x1, pw1, pb1, nullptr, h, N);
    agg_kernel<<<nodeblocks, B, 0, stream>>>(h, offsets, edata, agg, N);
    mm_kernel<64, 0, 0, 0><<<mmblocks, B, 0, stream>>>(h, f1w1, f1b1, nullptr, out, N);
    mm_kernel<64, 2, 1, 0><<<mmblocks, B, 0, stream>>>(agg, f2w1, f2b1, out, out, N);
}